// Round 1
// baseline (217.084 us; speedup 1.0000x reference)
//
#include <hip/hip_runtime.h>

#define NUM_C 1000
#define NUM_A 512

// Workspace layout (bytes):
//   [0,      4096)   counts[1024]  (int)
//   [4096,   8192)   starts[1024]  (int)
//   [8192,  12288)   cursor[1024]  (int)
//   [12288, ...  )   rowlist[N]    (int)

__global__ void hist_kernel(const int* __restrict__ labels, int* __restrict__ counts, int n) {
    int i = blockIdx.x * blockDim.x + threadIdx.x;
    int stride = gridDim.x * blockDim.x;
    for (; i < n; i += stride) {
        int lab = labels[i];
        atomicAdd(&counts[lab], 1);
    }
}

__global__ void scan_kernel(const int* __restrict__ counts, int* __restrict__ starts,
                            int* __restrict__ cursor) {
    __shared__ int buf[1024];
    int t = threadIdx.x;
    int v = (t < NUM_C) ? counts[t] : 0;
    buf[t] = v;
    __syncthreads();
    // Hillis-Steele inclusive scan over 1024 elements
    for (int off = 1; off < 1024; off <<= 1) {
        int x = (t >= off) ? buf[t - off] : 0;
        __syncthreads();
        buf[t] += x;
        __syncthreads();
    }
    int excl = buf[t] - v;  // exclusive prefix
    if (t < NUM_C) {
        starts[t] = excl;
        cursor[t] = excl;
    }
}

__global__ void scatter_kernel(const int* __restrict__ labels, int* __restrict__ cursor,
                               int* __restrict__ rowlist, int n) {
    int i = blockIdx.x * blockDim.x + threadIdx.x;
    int stride = gridDim.x * blockDim.x;
    for (; i < n; i += stride) {
        int lab = labels[i];
        int pos = atomicAdd(&cursor[lab], 1);
        rowlist[pos] = i;
    }
}

// One block per class; 256 threads, each owns 2 columns (float2).
__global__ __launch_bounds__(256) void reduce_kernel(
    const float* __restrict__ features,
    const int* __restrict__ starts, const int* __restrict__ counts,
    const int* __restrict__ rowlist, float* __restrict__ out) {
    int c = blockIdx.x;
    int t = threadIdx.x;            // column pair index: cols 2t, 2t+1
    int start = starts[c];
    int cnt = counts[c];

    float2 acc = make_float2(0.f, 0.f);
    const float2* F2 = reinterpret_cast<const float2*>(features);
    // features row r as float2: F2[r * 256 + t]

    int k = 0;
    for (; k + 4 <= cnt; k += 4) {
        int r0 = rowlist[start + k + 0];
        int r1 = rowlist[start + k + 1];
        int r2 = rowlist[start + k + 2];
        int r3 = rowlist[start + k + 3];
        float2 v0 = F2[(size_t)r0 * (NUM_A / 2) + t];
        float2 v1 = F2[(size_t)r1 * (NUM_A / 2) + t];
        float2 v2 = F2[(size_t)r2 * (NUM_A / 2) + t];
        float2 v3 = F2[(size_t)r3 * (NUM_A / 2) + t];
        acc.x += v0.x + v1.x + v2.x + v3.x;
        acc.y += v0.y + v1.y + v2.y + v3.y;
    }
    for (; k < cnt; ++k) {
        int r = rowlist[start + k];
        float2 v = F2[(size_t)r * (NUM_A / 2) + t];
        acc.x += v.x;
        acc.y += v.y;
    }

    float denom = (cnt > 0) ? (float)cnt : 1.0f;
    float2 res = make_float2(acc.x / denom, acc.y / denom);
    reinterpret_cast<float2*>(out)[(size_t)c * (NUM_A / 2) + t] = res;
}

extern "C" void kernel_launch(void* const* d_in, const int* in_sizes, int n_in,
                              void* d_out, int out_size, void* d_ws, size_t ws_size,
                              hipStream_t stream) {
    const float* features = (const float*)d_in[0];
    const int* labels = (const int*)d_in[1];
    float* out = (float*)d_out;
    int n = in_sizes[1];  // number of rows / labels

    char* ws = (char*)d_ws;
    int* counts  = (int*)(ws + 0);
    int* starts  = (int*)(ws + 4096);
    int* cursor  = (int*)(ws + 8192);
    int* rowlist = (int*)(ws + 12288);

    // zero the counts region
    hipMemsetAsync(counts, 0, 4096, stream);

    int blocks = (n + 255) / 256;
    if (blocks > 1024) blocks = 1024;

    hist_kernel<<<blocks, 256, 0, stream>>>(labels, counts, n);
    scan_kernel<<<1, 1024, 0, stream>>>(counts, starts, cursor);
    scatter_kernel<<<blocks, 256, 0, stream>>>(labels, cursor, rowlist, n);
    reduce_kernel<<<NUM_C, 256, 0, stream>>>(features, starts, counts, rowlist, out);
}